// Round 10
// baseline (309.154 us; speedup 1.0000x reference)
//
#include <hip/hip_runtime.h>

#define B_   8
#define CIN  512
#define NN_  4096
#define DD   256
#define KK   2048
#define KSPLIT 4
#define KPER (KK / KSPLIT)   // 512
#define NG   (B_ * NN_)      // 32768 total samples

typedef _Float16 f16x8 __attribute__((ext_vector_type(8)));
typedef _Float16 f16x4 __attribute__((ext_vector_type(4)));
typedef float    f32x16 __attribute__((ext_vector_type(16)));

#define MFMA16 __builtin_amdgcn_mfma_f32_32x32x16_f16

// async global->LDS, 16B per lane; LDS dest is wave-uniform base + lane*16
#define GLDS16(gp, lp) __builtin_amdgcn_global_load_lds( \
    (const __attribute__((address_space(1))) void*)(gp), \
    (__attribute__((address_space(3))) void*)(lp), 16, 0, 0)

// order-preserving float->u32 transform (total order, matches < on floats)
__device__ __forceinline__ unsigned ford(float f) {
  unsigned u = __float_as_uint(f);
  return (u & 0x80000000u) ? ~u : (u | 0x80000000u);
}

// ---------- kernel 0: fused {esq + emb split} | {out_numer=G*ema_numer ; mind64=~0 ; hist=0 ; done=0} ----------
__global__ __launch_bounds__(256) void k_init0(const float* __restrict__ emb,
                                               const float* __restrict__ ema_numer,
                                               float* __restrict__ esq,
                                               _Float16* __restrict__ emb_h,
                                               _Float16* __restrict__ emb_l,
                                               float* __restrict__ out_numer,
                                               unsigned* __restrict__ mind64w,
                                               int* __restrict__ hist,
                                               int* __restrict__ done) {
  const int bid = blockIdx.x;
  const int t = threadIdx.x;
  if (bid < KK / 4) {
    int lane = t & 63;
    int k = bid * 4 + (t >> 6);
    float4 v = *(const float4*)&emb[(size_t)k * DD + 4 * lane];
    float s = v.x * v.x + v.y * v.y + v.z * v.z + v.w * v.w;
    f16x4 h, l;
    float* vp = (float*)&v;
#pragma unroll
    for (int i = 0; i < 4; i++) {
      _Float16 hh = (_Float16)vp[i];
      h[i] = hh;
      l[i] = (_Float16)(vp[i] - (float)hh);
    }
    *(f16x4*)&emb_h[(size_t)k * DD + 4 * lane] = h;
    *(f16x4*)&emb_l[(size_t)k * DD + 4 * lane] = l;
    for (int off = 32; off > 0; off >>= 1) s += __shfl_down(s, off, 64);
    if (lane == 0) esq[k] = s;
  } else {
    int i = (bid - KK / 4) * 256 + t;
    if (i < KK * DD) out_numer[i] = 0.99f * ema_numer[i];
    else {
      int j = i - KK * DD;
      if (j < 2 * NG) mind64w[j] = 0xFFFFFFFFu;
      else if (j < 2 * NG + KK) hist[j - 2 * NG] = 0;
      else done[j - 2 * NG - KK] = 0;
    }
  }
}

// ---------- kernel 2: MFMA split-f16 conv: zeT_{h,l}[b,n,d] = sum_c W[d,c] z[b,c,n] ----------
__global__ __launch_bounds__(256) void k_ze(const float* __restrict__ W,
                                            const float* __restrict__ z,
                                            _Float16* __restrict__ zeT_h,
                                            _Float16* __restrict__ zeT_l) {
  __shared__ __align__(16) char sm[69632];
  const int t = threadIdx.x;
  const int w = t >> 6, lane = t & 63;
  const int lr = lane & 31, lh = lane >> 5;
  const int wm = w & 1, wn = w >> 1;
  const int swz = (lr >> 1) & 3;
  const int b = blockIdx.z, d0 = blockIdx.y * 128, n0 = blockIdx.x * 128;

  auto stageA = [&](int buf, int c0) {
    _Float16* Ah = (_Float16*)(sm + buf * 8192);
    _Float16* Al = (_Float16*)(sm + 16384 + buf * 8192);
#pragma unroll
    for (int i = 0; i < 4; i++) {
      int fid = i * 256 + t;
      int d = fid >> 3, q8 = fid & 7;
      float4 v = *(const float4*)&W[(size_t)(d0 + d) * CIN + c0 + 4 * q8];
      float* vp = (float*)&v;
      f16x4 h, l;
#pragma unroll
      for (int e = 0; e < 4; e++) {
        _Float16 hh = (_Float16)vp[e];
        h[e] = hh;
        l[e] = (_Float16)(vp[e] - (float)hh);
      }
      int p16 = (q8 >> 1) ^ ((d >> 1) & 3);
      int off = d * 32 + p16 * 8 + (q8 & 1) * 4;
      *(f16x4*)&Ah[off] = h;
      *(f16x4*)&Al[off] = l;
    }
  };

  auto stageZ = [&](int buf, int c0) {
    const int n_l = t & 127, cg = t >> 7;
    const float* gp = z + ((size_t)b * CIN + c0 + cg * 16) * NN_ + n0 + n_l;
    float v[16];
#pragma unroll
    for (int j = 0; j < 16; j++) v[j] = gp[(size_t)j * NN_];
    _Float16* Zh = (_Float16*)(sm + 32768 + buf * 8192);
    _Float16* Zl = (_Float16*)(sm + 49152 + buf * 8192);
#pragma unroll
    for (int q = 0; q < 2; q++) {
      f16x8 h, l;
#pragma unroll
      for (int e = 0; e < 8; e++) {
        float x = v[q * 8 + e];
        _Float16 hh = (_Float16)x;
        h[e] = hh;
        l[e] = (_Float16)(x - (float)hh);
      }
      int p = (cg * 2 + q) ^ ((n_l >> 1) & 3);
      *(f16x8*)&Zh[n_l * 32 + p * 8] = h;
      *(f16x8*)&Zl[n_l * 32 + p * 8] = l;
    }
  };

  f32x16 acc[2][2];
#pragma unroll
  for (int mt = 0; mt < 2; mt++)
#pragma unroll
    for (int nt = 0; nt < 2; nt++)
#pragma unroll
      for (int i = 0; i < 16; i++) acc[mt][nt][i] = 0.0f;

  stageA(0, 0);
  stageZ(0, 0);
  int buf = 0;
  for (int c0 = 0; c0 < CIN; c0 += 32) {
    __syncthreads();
    if (c0 + 32 < CIN) { stageA(buf ^ 1, c0 + 32); stageZ(buf ^ 1, c0 + 32); }
    const _Float16* WhB = (const _Float16*)(sm + buf * 8192);
    const _Float16* WlB = (const _Float16*)(sm + 16384 + buf * 8192);
    const _Float16* ZhB = (const _Float16*)(sm + 32768 + buf * 8192);
    const _Float16* ZlB = (const _Float16*)(sm + 49152 + buf * 8192);
#pragma unroll
    for (int s = 0; s < 2; s++) {
      const int p = (2 * s + lh) ^ swz;
      const int acol = p * 8;
      const int ar0 = (wm * 64 + lr) * 32 + acol;
      const int ar1 = (wm * 64 + 32 + lr) * 32 + acol;
      const int br0 = (wn * 64 + lr) * 32 + acol;
      const int br1 = (wn * 64 + 32 + lr) * 32 + acol;
      f16x8 ah0 = *(const f16x8*)(WhB + ar0);
      f16x8 ah1 = *(const f16x8*)(WhB + ar1);
      f16x8 al0 = *(const f16x8*)(WlB + ar0);
      f16x8 al1 = *(const f16x8*)(WlB + ar1);
      f16x8 bh0 = *(const f16x8*)(ZhB + br0);
      f16x8 bh1 = *(const f16x8*)(ZhB + br1);
      f16x8 bl0 = *(const f16x8*)(ZlB + br0);
      f16x8 bl1 = *(const f16x8*)(ZlB + br1);
      acc[0][0] = MFMA16(ah0, bh0, acc[0][0], 0, 0, 0);
      acc[0][1] = MFMA16(ah0, bh1, acc[0][1], 0, 0, 0);
      acc[1][0] = MFMA16(ah1, bh0, acc[1][0], 0, 0, 0);
      acc[1][1] = MFMA16(ah1, bh1, acc[1][1], 0, 0, 0);
      acc[0][0] = MFMA16(ah0, bl0, acc[0][0], 0, 0, 0);
      acc[0][1] = MFMA16(ah0, bl1, acc[0][1], 0, 0, 0);
      acc[1][0] = MFMA16(ah1, bl0, acc[1][0], 0, 0, 0);
      acc[1][1] = MFMA16(ah1, bl1, acc[1][1], 0, 0, 0);
      acc[0][0] = MFMA16(al0, bh0, acc[0][0], 0, 0, 0);
      acc[0][1] = MFMA16(al0, bh1, acc[0][1], 0, 0, 0);
      acc[1][0] = MFMA16(al1, bh0, acc[1][0], 0, 0, 0);
      acc[1][1] = MFMA16(al1, bh1, acc[1][1], 0, 0, 0);
    }
    buf ^= 1;
  }

  __syncthreads();
  _Float16* Eh = (_Float16*)sm;             // [128][132]
  _Float16* El = (_Float16*)(sm + 33792);
#pragma unroll
  for (int mt = 0; mt < 2; mt++)
#pragma unroll
    for (int nt = 0; nt < 2; nt++) {
      int n_l = wn * 64 + nt * 32 + lr;
#pragma unroll
      for (int g = 0; g < 4; g++) {
        int d_l = wm * 64 + mt * 32 + 8 * g + 4 * lh;
        f16x4 h, l;
#pragma unroll
        for (int e = 0; e < 4; e++) {
          float x = acc[mt][nt][4 * g + e];
          _Float16 hh = (_Float16)x;
          h[e] = hh;
          l[e] = (_Float16)(x - (float)hh);
        }
        *(f16x4*)&Eh[n_l * 132 + d_l] = h;
        *(f16x4*)&El[n_l * 132 + d_l] = l;
      }
    }
  __syncthreads();
  _Float16* gh = zeT_h + ((size_t)b * NN_ + n0) * DD + d0;
  _Float16* gl = zeT_l + ((size_t)b * NN_ + n0) * DD + d0;
#pragma unroll
  for (int i = 0; i < 16; i++) {
    int n = i * 8 + w * 2 + lh;
    int d = 4 * lr;
    *(f16x4*)&gh[(size_t)n * DD + d] = *(const f16x4*)&Eh[n * 132 + d];
    *(f16x4*)&gl[(size_t)n * DD + d] = *(const f16x4*)&El[n * 132 + d];
  }
}

// ---------- kernel 3: MFMA split-f16 partial argmin over one K-split ----------
// v2: ze (B-operand) read DIRECTLY global->VGPR (contiguous 16B/lane, no
// transpose needed) instead of LDS-staged -- halves LDS traffic (the measured
// bottleneck: 192KB/K-step/CU vs 384 MFMA cyc). B loads for step i+1 issue
// after step i's MFMAs; the __syncthreads vmcnt(0) drain covers their latency.
// emb (A) stays LDS-staged+swizzled (shared by 2 waves). LDS 69632->36864.
__global__ __launch_bounds__(256) void k_argmin(const _Float16* __restrict__ emb_h,
                                                const _Float16* __restrict__ emb_l,
                                                const _Float16* __restrict__ zeT_h,
                                                const _Float16* __restrict__ zeT_l,
                                                const float* __restrict__ esq,
                                                unsigned long long* __restrict__ mind64) {
  // Eh: [2][128][32] f16 @0 (16384) ; El @16384 ; esqs @32768 (2048) ;
  // pv @34816 (1024) ; pi @35840 (1024) -> 36864
  __shared__ __align__(16) char sm[36864];
  const int t = threadIdx.x;
  const int w = t >> 6, lane = t & 63;
  const int lr = lane & 31, lh = lane >> 5;
  const int wm = w & 1, wn = w >> 1;
  const int swz = (lr >> 1) & 3;
  const int b = blockIdx.y, n0 = blockIdx.x * 128, ks = blockIdx.z;
  const int kbase = ks * KPER;

  float* esqs = (float*)(sm + 32768);
  *(float2*)&esqs[2 * t] = *(const float2*)&esq[kbase + 2 * t];

  const _Float16* zb_h = zeT_h + ((size_t)b * NN_ + n0) * DD;
  const _Float16* zb_l = zeT_l + ((size_t)b * NN_ + n0) * DD;

  // A (emb) staging only: XOR-swizzled 64B rows as proven
  auto stage = [&](int buf, int kt, int dc) {
    const int k0 = kbase + kt * 128;
    const int q = lane & 3, rr = lane >> 2;
    const int g = q ^ ((rr >> 1) & 3);
    const int rb0 = 32 * w;
#pragma unroll
    for (int j = 0; j < 2; j++) {
      int rb = rb0 + 16 * j;
      int r = rb + rr;
      int col = dc + 8 * g;
      size_t eo = (size_t)(k0 + r) * DD + col;
      char* lb = sm + (size_t)buf * 8192 + rb * 64;
      GLDS16(emb_h + eo, lb);
      GLDS16(emb_l + eo, lb + 16384);
    }
  };

  // B (ze) fragments: direct global loads, one set live at a time (32 VGPR)
  f16x8 rbh0[2], rbh1[2], rbl0[2], rbl1[2];
  const size_t zr0 = (size_t)(wn * 64 + lr) * DD;
  const size_t zr1 = (size_t)(wn * 64 + 32 + lr) * DD;
  auto loadB = [&](int dc2) {
#pragma unroll
    for (int s = 0; s < 2; s++) {
      int col = dc2 + 16 * s + 8 * lh;
      rbh0[s] = *(const f16x8*)(zb_h + zr0 + col);
      rbh1[s] = *(const f16x8*)(zb_h + zr1 + col);
      rbl0[s] = *(const f16x8*)(zb_l + zr0 + col);
      rbl1[s] = *(const f16x8*)(zb_l + zr1 + col);
    }
  };

  f32x16 vzero;
#pragma unroll
  for (int i = 0; i < 16; i++) vzero[i] = 0.0f;

  float bestv[2];
  int   besti[2];
  bestv[0] = bestv[1] = 3.4e38f;
  besti[0] = besti[1] = 0;

  stage(0, 0, 0);
  loadB(0);
  int buf = 0;
  for (int kt = 0; kt < 4; kt++) {
    f32x16 acc00 = vzero, acc01 = vzero, acc10 = vzero, acc11 = vzero;
    for (int dc = 0; dc < DD; dc += 32) {
      __syncthreads();
      if (dc + 32 < DD) stage(buf ^ 1, kt, dc + 32);
      else if (kt < 3) stage(buf ^ 1, kt + 1, 0);
      const _Float16* EHb = (const _Float16*)(sm + buf * 8192);
      const _Float16* ELb = (const _Float16*)(sm + 16384 + buf * 8192);
#pragma unroll
      for (int s = 0; s < 2; s++) {
        const int p = (2 * s + lh) ^ swz;   // swizzled 16B chunk (A only)
        const int acol = p * 8;
        const int ar0 = (wm * 64 + lr) * 32 + acol;
        const int ar1 = (wm * 64 + 32 + lr) * 32 + acol;
        f16x8 ah0 = *(const f16x8*)(EHb + ar0);
        f16x8 ah1 = *(const f16x8*)(EHb + ar1);
        f16x8 al0 = *(const f16x8*)(ELb + ar0);
        f16x8 al1 = *(const f16x8*)(ELb + ar1);
        acc00 = MFMA16(ah0, rbh0[s], acc00, 0, 0, 0);
        acc01 = MFMA16(ah0, rbh1[s], acc01, 0, 0, 0);
        acc10 = MFMA16(ah1, rbh0[s], acc10, 0, 0, 0);
        acc11 = MFMA16(ah1, rbh1[s], acc11, 0, 0, 0);
        acc00 = MFMA16(ah0, rbl0[s], acc00, 0, 0, 0);
        acc01 = MFMA16(ah0, rbl1[s], acc01, 0, 0, 0);
        acc10 = MFMA16(ah1, rbl0[s], acc10, 0, 0, 0);
        acc11 = MFMA16(ah1, rbl1[s], acc11, 0, 0, 0);
        acc00 = MFMA16(al0, rbh0[s], acc00, 0, 0, 0);
        acc01 = MFMA16(al0, rbh1[s], acc01, 0, 0, 0);
        acc10 = MFMA16(al1, rbh0[s], acc10, 0, 0, 0);
        acc11 = MFMA16(al1, rbh1[s], acc11, 0, 0, 0);
      }
      // issue next K-step's B loads (B depends only on dc; wraps to 0 per kt).
      // WAR on rb* keeps these after the MFMAs; next __syncthreads drains them.
      if (!(kt == 3 && dc + 32 >= DD)) {
        int ndc = (dc + 32 < DD) ? dc + 32 : 0;
        loadB(ndc);
      }
      buf ^= 1;
    }
#pragma unroll
    for (int mt = 0; mt < 2; mt++)
#pragma unroll
      for (int nt = 0; nt < 2; nt++) {
        const f32x16& a = (mt == 0) ? (nt == 0 ? acc00 : acc01)
                                    : (nt == 0 ? acc10 : acc11);
#pragma unroll
        for (int r = 0; r < 16; r++) {
          int kl = kt * 128 + wm * 64 + mt * 32 + (r & 3) + 8 * (r >> 2) + 4 * lh;
          float d2 = esqs[kl] - 2.0f * a[r];
          int kg = kbase + kl;
          if (d2 < bestv[nt] || (d2 == bestv[nt] && kg < besti[nt])) {
            bestv[nt] = d2; besti[nt] = kg;
          }
        }
      }
  }

#pragma unroll
  for (int nt = 0; nt < 2; nt++) {
    float ov = __shfl_xor(bestv[nt], 32, 64);
    int   oi = __shfl_xor(besti[nt], 32, 64);
    if (ov < bestv[nt] || (ov == bestv[nt] && oi < besti[nt])) {
      bestv[nt] = ov; besti[nt] = oi;
    }
  }
  float* pv = (float*)(sm + 34816);
  int*   pi = (int*)(sm + 35840);
  __syncthreads();
  if (lh == 0) {
#pragma unroll
    for (int nt = 0; nt < 2; nt++) {
      pv[(w * 2 + nt) * 32 + lr] = bestv[nt];
      pi[(w * 2 + nt) * 32 + lr] = besti[nt];
    }
  }
  __syncthreads();
  if (t < 128) {
    int wn2 = t >> 6, nt = (t >> 5) & 1, nl = t & 31;
    int i0 = ((2 * wn2 + 0) * 2 + nt) * 32 + nl;
    int i1 = ((2 * wn2 + 1) * 2 + nt) * 32 + nl;
    float v0 = pv[i0], v1 = pv[i1];
    int   j0 = pi[i0], j1 = pi[i1];
    if (v1 < v0 || (v1 == v0 && j1 < j0)) { v0 = v1; j0 = j1; }
    unsigned long long pk = ((unsigned long long)ford(v0) << 32) | (unsigned)j0;
    atomicMin(&mind64[(size_t)b * NN_ + n0 + t], pk);
  }
}

// ---------- kernel 5: 16-block histogram of mind64 -> (last block) scan -> cursor ; out_denom ----------
__global__ __launch_bounds__(256) void k_scan(const unsigned long long* __restrict__ mind64,
                                              const float* __restrict__ ema_denom,
                                              int* __restrict__ hist,
                                              int* __restrict__ done,
                                              int* __restrict__ cursor,
                                              float* __restrict__ out_denom) {
  __shared__ int h[KK];
  __shared__ int ps[256];
  __shared__ int lastFlag;
  const int t = threadIdx.x;
#pragma unroll
  for (int i = 0; i < 8; i++) h[t + 256 * i] = 0;
  __syncthreads();
  const int base = blockIdx.x * (NG / 16);
#pragma unroll
  for (int i = 0; i < NG / 16 / 256; i++) {   // 8 iters of 256
    int idx = (int)(mind64[base + i * 256 + t] & 0xFFFFFFFFULL);
    atomicAdd(&h[idx], 1);
  }
  __syncthreads();
#pragma unroll
  for (int i = 0; i < 8; i++) {
    int v = h[t + 256 * i];
    if (v) atomicAdd(&hist[t + 256 * i], v);
  }
  __threadfence();
  __syncthreads();
  if (t == 0) lastFlag = (atomicAdd(done, 1) == 15);
  __syncthreads();
  if (!lastFlag) return;

  // last block: read hist coherently (device-scope atomic read), scan, emit
  int c[8], s = 0;
#pragma unroll
  for (int e = 0; e < 8; e++) { c[e] = atomicAdd(&hist[8 * t + e], 0); s += c[e]; }
  ps[t] = s;
  __syncthreads();
  for (int off = 1; off < 256; off <<= 1) {
    int v = (t >= off) ? ps[t - off] : 0;
    __syncthreads();
    ps[t] += v;
    __syncthreads();
  }
  int run = ps[t] - s;
#pragma unroll
  for (int e = 0; e < 8; e++) {
    cursor[8 * t + e] = run;
    out_denom[8 * t + e] = 0.99f * ema_denom[8 * t + e]
                         + 0.009999999776482582f * (float)c[e];
    run += c[e];
  }
}

// ---------- kernel 6: out[b,d,n] = emb[mind[b,n], d] ; fused pos-scatter ----------
__global__ __launch_bounds__(256) void k_out(const float* __restrict__ emb,
                                             const unsigned long long* __restrict__ mind64,
                                             float* __restrict__ out,
                                             int* __restrict__ cursor,
                                             int* __restrict__ sortp) {
  __shared__ __align__(16) float E[64][257];
  __shared__ int idxl[64];
  const int t = threadIdx.x;
  const int b  = blockIdx.y;
  const int n0 = blockIdx.x * 64;
  if (t < 64) idxl[t] = (int)(mind64[(size_t)b * NN_ + n0 + t] & 0xFFFFFFFFULL);
  __syncthreads();

  // fused k_pos: scatter these 64 samples into sorted order
  if (t < 64) {
    int g = b * NN_ + n0 + t;
    int k = idxl[t];
    int p = atomicAdd(&cursor[k], 1);
    sortp[p] = (k << 15) | g;
  }

  for (int i = 0; i < 16; i++) {
    int cid = t + 256 * i;
    int r = cid >> 6, q = cid & 63;
    float4 v = *(const float4*)&emb[(size_t)idxl[r] * DD + 4 * q];
    float* vp = (float*)&v;
    E[r][4 * q + 0] = vp[0];
    E[r][4 * q + 1] = vp[1];
    E[r][4 * q + 2] = vp[2];
    E[r][4 * q + 3] = vp[3];
  }
  __syncthreads();
  const int nq = t & 15, dg = t >> 4;
  float* outb = out + (size_t)b * DD * NN_ + n0;
#pragma unroll
  for (int i = 0; i < 16; i++) {
    int d = i * 16 + dg;
    float4 v = make_float4(E[4 * nq + 0][d], E[4 * nq + 1][d],
                           E[4 * nq + 2][d], E[4 * nq + 3][d]);
    *(float4*)&outb[(size_t)d * NN_ + 4 * nq] = v;
  }
}

// ---------- kernel 7: segment-sum over sorted runs -> out_numer += OG*z_sum ----------
__global__ __launch_bounds__(256) void k_zsum(const int* __restrict__ sortp,
                                              const _Float16* __restrict__ zeT_h,
                                              const _Float16* __restrict__ zeT_l,
                                              float* __restrict__ out_numer) {
  const float OG = 0.009999999776482582f;
  __shared__ int sg[128];
  const int t = threadIdx.x;
  const int w = t >> 6, lane = t & 63;
  if (t < 128) sg[t] = sortp[blockIdx.x * 128 + t];
  __syncthreads();
  const int base = w * 32;
  float acc[4] = {0.f, 0.f, 0.f, 0.f};
  int cur = sg[base] >> 15;
  for (int j = 0; j < 32; j++) {
    int e = sg[base + j];
    int k = e >> 15, g = e & 32767;
    if (k != cur) {
      float* zs = &out_numer[(size_t)cur * DD + 4 * lane];
#pragma unroll
      for (int x = 0; x < 4; x++) { atomicAdd(&zs[x], OG * acc[x]); acc[x] = 0.f; }
      cur = k;
    }
    f16x4 h = *(const f16x4*)&zeT_h[(size_t)g * DD + 4 * lane];
    f16x4 l = *(const f16x4*)&zeT_l[(size_t)g * DD + 4 * lane];
#pragma unroll
    for (int x = 0; x < 4; x++) acc[x] += (float)h[x] + (float)l[x];
  }
  float* zs = &out_numer[(size_t)cur * DD + 4 * lane];
#pragma unroll
  for (int x = 0; x < 4; x++) atomicAdd(&zs[x], OG * acc[x]);
}

extern "C" void kernel_launch(void* const* d_in, const int* in_sizes, int n_in,
                              void* d_out, int out_size, void* d_ws, size_t ws_size,
                              hipStream_t stream) {
  (void)in_sizes; (void)n_in; (void)out_size; (void)ws_size;
  const float* z         = (const float*)d_in[0];
  const float* W         = (const float*)d_in[1];
  const float* emb       = (const float*)d_in[2];
  const float* ema_numer = (const float*)d_in[3];
  const float* ema_denom = (const float*)d_in[4];

  float* out       = (float*)d_out;                        // (8,256,4096)
  float* out_numer = out + (size_t)B_ * DD * NN_;
  float* out_denom = out_numer + (size_t)KK * DD;

  const size_t ZET = (size_t)B_ * NN_ * DD;                // 8388608
  _Float16* zeT_h = (_Float16*)d_ws;                       // 16 MB
  _Float16* zeT_l = zeT_h + ZET;                           // 16 MB
  float* esq    = (float*)(zeT_l + ZET);                   // 2048 f
  int*   cursor = (int*)(esq + KK);                        // 2048 i
  int*   sortp  = cursor + KK;                             // 32768 i
  unsigned long long* mind64 = (unsigned long long*)(sortp + NG);  // 32768 u64 (8B-aligned)
  int*   hist   = (int*)(mind64 + NG);                     // 2048 i
  int*   done   = hist + KK;                               // 256 i
  _Float16* emb_h = (_Float16*)(done + 256);               // 524288 f16
  _Float16* emb_l = emb_h + (size_t)KK * DD;               // 524288 f16

  // k_init0 grid: 512 esq-blocks + (KK*DD + 2*NG + KK + 256)/256 init-blocks
  const int initBlocks = KK / 4 + (KK * DD + 2 * NG + KK + 256) / 256;   // 512 + 2313
  k_init0<<<dim3(initBlocks), 256, 0, stream>>>(emb, ema_numer, esq, emb_h, emb_l,
                                                out_numer, (unsigned*)mind64, hist, done);
  k_ze<<<dim3(NN_ / 128, DD / 128, B_), 256, 0, stream>>>(W, z, zeT_h, zeT_l);
  k_argmin<<<dim3(NN_ / 128, B_, KSPLIT), 256, 0, stream>>>(emb_h, emb_l, zeT_h, zeT_l,
                                                            esq, mind64);
  k_scan<<<dim3(16), 256, 0, stream>>>(mind64, ema_denom, hist, done, cursor, out_denom);
  k_out<<<dim3(NN_ / 64, B_), 256, 0, stream>>>(emb, mind64, out, cursor, sortp);
  k_zsum<<<dim3(NG / 128), 256, 0, stream>>>(sortp, zeT_h, zeT_l, out_numer);
}

// Round 11
// 279.367 us; speedup vs baseline: 1.1066x; 1.1066x over previous
//
#include <hip/hip_runtime.h>

#define B_   8
#define CIN  512
#define NN_  4096
#define DD   256
#define KK   2048
#define KSPLIT 4
#define KPER (KK / KSPLIT)   // 512
#define NG   (B_ * NN_)      // 32768 total samples

typedef _Float16 f16x8 __attribute__((ext_vector_type(8)));
typedef _Float16 f16x4 __attribute__((ext_vector_type(4)));
typedef float    f32x16 __attribute__((ext_vector_type(16)));

#define MFMA16 __builtin_amdgcn_mfma_f32_32x32x16_f16

// async global->LDS, 16B per lane; LDS dest is wave-uniform base + lane*16
#define GLDS16(gp, lp) __builtin_amdgcn_global_load_lds( \
    (const __attribute__((address_space(1))) void*)(gp), \
    (__attribute__((address_space(3))) void*)(lp), 16, 0, 0)

// order-preserving float->u32 transform (total order, matches < on floats)
__device__ __forceinline__ unsigned ford(float f) {
  unsigned u = __float_as_uint(f);
  return (u & 0x80000000u) ? ~u : (u | 0x80000000u);
}

// ---------- kernel 0: fused {esq + emb split} | {out_numer=G*ema_numer ; mind64=~0 ; hist=0 ; done=0} ----------
__global__ __launch_bounds__(256) void k_init0(const float* __restrict__ emb,
                                               const float* __restrict__ ema_numer,
                                               float* __restrict__ esq,
                                               _Float16* __restrict__ emb_h,
                                               _Float16* __restrict__ emb_l,
                                               float* __restrict__ out_numer,
                                               unsigned* __restrict__ mind64w,
                                               int* __restrict__ hist,
                                               int* __restrict__ done) {
  const int bid = blockIdx.x;
  const int t = threadIdx.x;
  if (bid < KK / 4) {
    int lane = t & 63;
    int k = bid * 4 + (t >> 6);
    float4 v = *(const float4*)&emb[(size_t)k * DD + 4 * lane];
    float s = v.x * v.x + v.y * v.y + v.z * v.z + v.w * v.w;
    f16x4 h, l;
    float* vp = (float*)&v;
#pragma unroll
    for (int i = 0; i < 4; i++) {
      _Float16 hh = (_Float16)vp[i];
      h[i] = hh;
      l[i] = (_Float16)(vp[i] - (float)hh);
    }
    *(f16x4*)&emb_h[(size_t)k * DD + 4 * lane] = h;
    *(f16x4*)&emb_l[(size_t)k * DD + 4 * lane] = l;
    for (int off = 32; off > 0; off >>= 1) s += __shfl_down(s, off, 64);
    if (lane == 0) esq[k] = s;
  } else {
    int i = (bid - KK / 4) * 256 + t;
    if (i < KK * DD) out_numer[i] = 0.99f * ema_numer[i];
    else {
      int j = i - KK * DD;
      if (j < 2 * NG) mind64w[j] = 0xFFFFFFFFu;
      else if (j < 2 * NG + KK) hist[j - 2 * NG] = 0;
      else done[j - 2 * NG - KK] = 0;
    }
  }
}

// ---------- kernel 2: MFMA split-f16 conv: zeT_{h,l}[b,n,d] = sum_c W[d,c] z[b,c,n] ----------
__global__ __launch_bounds__(256) void k_ze(const float* __restrict__ W,
                                            const float* __restrict__ z,
                                            _Float16* __restrict__ zeT_h,
                                            _Float16* __restrict__ zeT_l) {
  __shared__ __align__(16) char sm[69632];
  const int t = threadIdx.x;
  const int w = t >> 6, lane = t & 63;
  const int lr = lane & 31, lh = lane >> 5;
  const int wm = w & 1, wn = w >> 1;
  const int swz = (lr >> 1) & 3;
  const int b = blockIdx.z, d0 = blockIdx.y * 128, n0 = blockIdx.x * 128;

  auto stageA = [&](int buf, int c0) {
    _Float16* Ah = (_Float16*)(sm + buf * 8192);
    _Float16* Al = (_Float16*)(sm + 16384 + buf * 8192);
#pragma unroll
    for (int i = 0; i < 4; i++) {
      int fid = i * 256 + t;
      int d = fid >> 3, q8 = fid & 7;
      float4 v = *(const float4*)&W[(size_t)(d0 + d) * CIN + c0 + 4 * q8];
      float* vp = (float*)&v;
      f16x4 h, l;
#pragma unroll
      for (int e = 0; e < 4; e++) {
        _Float16 hh = (_Float16)vp[e];
        h[e] = hh;
        l[e] = (_Float16)(vp[e] - (float)hh);
      }
      int p16 = (q8 >> 1) ^ ((d >> 1) & 3);
      int off = d * 32 + p16 * 8 + (q8 & 1) * 4;
      *(f16x4*)&Ah[off] = h;
      *(f16x4*)&Al[off] = l;
    }
  };

  auto stageZ = [&](int buf, int c0) {
    const int n_l = t & 127, cg = t >> 7;
    const float* gp = z + ((size_t)b * CIN + c0 + cg * 16) * NN_ + n0 + n_l;
    float v[16];
#pragma unroll
    for (int j = 0; j < 16; j++) v[j] = gp[(size_t)j * NN_];
    _Float16* Zh = (_Float16*)(sm + 32768 + buf * 8192);
    _Float16* Zl = (_Float16*)(sm + 49152 + buf * 8192);
#pragma unroll
    for (int q = 0; q < 2; q++) {
      f16x8 h, l;
#pragma unroll
      for (int e = 0; e < 8; e++) {
        float x = v[q * 8 + e];
        _Float16 hh = (_Float16)x;
        h[e] = hh;
        l[e] = (_Float16)(x - (float)hh);
      }
      int p = (cg * 2 + q) ^ ((n_l >> 1) & 3);
      *(f16x8*)&Zh[n_l * 32 + p * 8] = h;
      *(f16x8*)&Zl[n_l * 32 + p * 8] = l;
    }
  };

  f32x16 acc[2][2];
#pragma unroll
  for (int mt = 0; mt < 2; mt++)
#pragma unroll
    for (int nt = 0; nt < 2; nt++)
#pragma unroll
      for (int i = 0; i < 16; i++) acc[mt][nt][i] = 0.0f;

  stageA(0, 0);
  stageZ(0, 0);
  int buf = 0;
  for (int c0 = 0; c0 < CIN; c0 += 32) {
    __syncthreads();
    if (c0 + 32 < CIN) { stageA(buf ^ 1, c0 + 32); stageZ(buf ^ 1, c0 + 32); }
    const _Float16* WhB = (const _Float16*)(sm + buf * 8192);
    const _Float16* WlB = (const _Float16*)(sm + 16384 + buf * 8192);
    const _Float16* ZhB = (const _Float16*)(sm + 32768 + buf * 8192);
    const _Float16* ZlB = (const _Float16*)(sm + 49152 + buf * 8192);
#pragma unroll
    for (int s = 0; s < 2; s++) {
      const int p = (2 * s + lh) ^ swz;
      const int acol = p * 8;
      const int ar0 = (wm * 64 + lr) * 32 + acol;
      const int ar1 = (wm * 64 + 32 + lr) * 32 + acol;
      const int br0 = (wn * 64 + lr) * 32 + acol;
      const int br1 = (wn * 64 + 32 + lr) * 32 + acol;
      f16x8 ah0 = *(const f16x8*)(WhB + ar0);
      f16x8 ah1 = *(const f16x8*)(WhB + ar1);
      f16x8 al0 = *(const f16x8*)(WlB + ar0);
      f16x8 al1 = *(const f16x8*)(WlB + ar1);
      f16x8 bh0 = *(const f16x8*)(ZhB + br0);
      f16x8 bh1 = *(const f16x8*)(ZhB + br1);
      f16x8 bl0 = *(const f16x8*)(ZlB + br0);
      f16x8 bl1 = *(const f16x8*)(ZlB + br1);
      acc[0][0] = MFMA16(ah0, bh0, acc[0][0], 0, 0, 0);
      acc[0][1] = MFMA16(ah0, bh1, acc[0][1], 0, 0, 0);
      acc[1][0] = MFMA16(ah1, bh0, acc[1][0], 0, 0, 0);
      acc[1][1] = MFMA16(ah1, bh1, acc[1][1], 0, 0, 0);
      acc[0][0] = MFMA16(ah0, bl0, acc[0][0], 0, 0, 0);
      acc[0][1] = MFMA16(ah0, bl1, acc[0][1], 0, 0, 0);
      acc[1][0] = MFMA16(ah1, bl0, acc[1][0], 0, 0, 0);
      acc[1][1] = MFMA16(ah1, bl1, acc[1][1], 0, 0, 0);
      acc[0][0] = MFMA16(al0, bh0, acc[0][0], 0, 0, 0);
      acc[0][1] = MFMA16(al0, bh1, acc[0][1], 0, 0, 0);
      acc[1][0] = MFMA16(al1, bh0, acc[1][0], 0, 0, 0);
      acc[1][1] = MFMA16(al1, bh1, acc[1][1], 0, 0, 0);
    }
    buf ^= 1;
  }

  __syncthreads();
  _Float16* Eh = (_Float16*)sm;             // [128][132]
  _Float16* El = (_Float16*)(sm + 33792);
#pragma unroll
  for (int mt = 0; mt < 2; mt++)
#pragma unroll
    for (int nt = 0; nt < 2; nt++) {
      int n_l = wn * 64 + nt * 32 + lr;
#pragma unroll
      for (int g = 0; g < 4; g++) {
        int d_l = wm * 64 + mt * 32 + 8 * g + 4 * lh;
        f16x4 h, l;
#pragma unroll
        for (int e = 0; e < 4; e++) {
          float x = acc[mt][nt][4 * g + e];
          _Float16 hh = (_Float16)x;
          h[e] = hh;
          l[e] = (_Float16)(x - (float)hh);
        }
        *(f16x4*)&Eh[n_l * 132 + d_l] = h;
        *(f16x4*)&El[n_l * 132 + d_l] = l;
      }
    }
  __syncthreads();
  _Float16* gh = zeT_h + ((size_t)b * NN_ + n0) * DD + d0;
  _Float16* gl = zeT_l + ((size_t)b * NN_ + n0) * DD + d0;
#pragma unroll
  for (int i = 0; i < 16; i++) {
    int n = i * 8 + w * 2 + lh;
    int d = 4 * lr;
    *(f16x4*)&gh[(size_t)n * DD + d] = *(const f16x4*)&Eh[n * 132 + d];
    *(f16x4*)&gl[(size_t)n * DD + d] = *(const f16x4*)&El[n * 132 + d];
  }
}

// ---------- kernel 3: MFMA split-f16 partial argmin over one K-split ----------
// (proven 2-phase LDS-staged version, 124 VGPR / 2 WG/CU; epilogue merges
// across K-splits via packed (ordered-d2, idx) u64 atomicMin into mind64)
__global__ __launch_bounds__(256) void k_argmin(const _Float16* __restrict__ emb_h,
                                                const _Float16* __restrict__ emb_l,
                                                const _Float16* __restrict__ zeT_h,
                                                const _Float16* __restrict__ zeT_l,
                                                const float* __restrict__ esq,
                                                unsigned long long* __restrict__ mind64) {
  __shared__ __align__(16) char sm[69632];
  const int t = threadIdx.x;
  const int w = t >> 6, lane = t & 63;
  const int lr = lane & 31, lh = lane >> 5;
  const int wm = w & 1, wn = w >> 1;
  const int swz = (lr >> 1) & 3;
  const int b = blockIdx.y, n0 = blockIdx.x * 128, ks = blockIdx.z;
  const int kbase = ks * KPER;

  float* esqs = (float*)(sm + 65536);
  *(float2*)&esqs[2 * t] = *(const float2*)&esq[kbase + 2 * t];

  const _Float16* zb_h = zeT_h + ((size_t)b * NN_ + n0) * DD;
  const _Float16* zb_l = zeT_l + ((size_t)b * NN_ + n0) * DD;

  auto stage = [&](int buf, int kt, int dc) {
    const int k0 = kbase + kt * 128;
    const int q = lane & 3, rr = lane >> 2;
    const int g = q ^ ((rr >> 1) & 3);   // swizzled global 16B chunk for this lane
    const int rb0 = 32 * w;
#pragma unroll
    for (int j = 0; j < 2; j++) {
      int rb = rb0 + 16 * j;
      int r = rb + rr;
      int col = dc + 8 * g;
      size_t eo = (size_t)(k0 + r) * DD + col;
      size_t zo = (size_t)r * DD + col;
      char* lb = sm + (size_t)buf * 8192 + rb * 64;
      GLDS16(emb_h + eo, lb);
      GLDS16(emb_l + eo, lb + 16384);
      GLDS16(zb_h + zo, lb + 32768);
      GLDS16(zb_l + zo, lb + 49152);
    }
  };

  f32x16 vzero;
#pragma unroll
  for (int i = 0; i < 16; i++) vzero[i] = 0.0f;

  float bestv[2];
  int   besti[2];
  bestv[0] = bestv[1] = 3.4e38f;
  besti[0] = besti[1] = 0;

  stage(0, 0, 0);
  int buf = 0;
  for (int kt = 0; kt < 4; kt++) {
    f32x16 acc00 = vzero, acc01 = vzero, acc10 = vzero, acc11 = vzero;
    for (int dc = 0; dc < DD; dc += 32) {
      __syncthreads();
      if (dc + 32 < DD) stage(buf ^ 1, kt, dc + 32);
      else if (kt < 3) stage(buf ^ 1, kt + 1, 0);
      const _Float16* EHb = (const _Float16*)(sm + buf * 8192);
      const _Float16* ELb = (const _Float16*)(sm + 16384 + buf * 8192);
      const _Float16* ZHb = (const _Float16*)(sm + 32768 + buf * 8192);
      const _Float16* ZLb = (const _Float16*)(sm + 49152 + buf * 8192);
#pragma unroll
      for (int s = 0; s < 2; s++) {
        const int p = (2 * s + lh) ^ swz;   // swizzled 16B chunk
        const int acol = p * 8;
        const int ar0 = (wm * 64 + lr) * 32 + acol;
        const int ar1 = (wm * 64 + 32 + lr) * 32 + acol;
        const int br0 = (wn * 64 + lr) * 32 + acol;
        const int br1 = (wn * 64 + 32 + lr) * 32 + acol;
        f16x8 ah0 = *(const f16x8*)(EHb + ar0);
        f16x8 ah1 = *(const f16x8*)(EHb + ar1);
        f16x8 al0 = *(const f16x8*)(ELb + ar0);
        f16x8 al1 = *(const f16x8*)(ELb + ar1);
        f16x8 bh0 = *(const f16x8*)(ZHb + br0);
        f16x8 bh1 = *(const f16x8*)(ZHb + br1);
        f16x8 bl0 = *(const f16x8*)(ZLb + br0);
        f16x8 bl1 = *(const f16x8*)(ZLb + br1);
        acc00 = MFMA16(ah0, bh0, acc00, 0, 0, 0);
        acc01 = MFMA16(ah0, bh1, acc01, 0, 0, 0);
        acc10 = MFMA16(ah1, bh0, acc10, 0, 0, 0);
        acc11 = MFMA16(ah1, bh1, acc11, 0, 0, 0);
        acc00 = MFMA16(ah0, bl0, acc00, 0, 0, 0);
        acc01 = MFMA16(ah0, bl1, acc01, 0, 0, 0);
        acc10 = MFMA16(ah1, bl0, acc10, 0, 0, 0);
        acc11 = MFMA16(ah1, bl1, acc11, 0, 0, 0);
        acc00 = MFMA16(al0, bh0, acc00, 0, 0, 0);
        acc01 = MFMA16(al0, bh1, acc01, 0, 0, 0);
        acc10 = MFMA16(al1, bh0, acc10, 0, 0, 0);
        acc11 = MFMA16(al1, bh1, acc11, 0, 0, 0);
      }
      buf ^= 1;
    }
#pragma unroll
    for (int mt = 0; mt < 2; mt++)
#pragma unroll
      for (int nt = 0; nt < 2; nt++) {
        const f32x16& a = (mt == 0) ? (nt == 0 ? acc00 : acc01)
                                    : (nt == 0 ? acc10 : acc11);
#pragma unroll
        for (int r = 0; r < 16; r++) {
          int kl = kt * 128 + wm * 64 + mt * 32 + (r & 3) + 8 * (r >> 2) + 4 * lh;
          float d2 = esqs[kl] - 2.0f * a[r];
          int kg = kbase + kl;
          if (d2 < bestv[nt] || (d2 == bestv[nt] && kg < besti[nt])) {
            bestv[nt] = d2; besti[nt] = kg;
          }
        }
      }
  }

#pragma unroll
  for (int nt = 0; nt < 2; nt++) {
    float ov = __shfl_xor(bestv[nt], 32, 64);
    int   oi = __shfl_xor(besti[nt], 32, 64);
    if (ov < bestv[nt] || (ov == bestv[nt] && oi < besti[nt])) {
      bestv[nt] = ov; besti[nt] = oi;
    }
  }
  float* pv = (float*)(sm + 67584);
  int*   pi = (int*)(sm + 68608);
  __syncthreads();
  if (lh == 0) {
#pragma unroll
    for (int nt = 0; nt < 2; nt++) {
      pv[(w * 2 + nt) * 32 + lr] = bestv[nt];
      pi[(w * 2 + nt) * 32 + lr] = besti[nt];
    }
  }
  __syncthreads();
  if (t < 128) {
    int wn2 = t >> 6, nt = (t >> 5) & 1, nl = t & 31;
    int i0 = ((2 * wn2 + 0) * 2 + nt) * 32 + nl;
    int i1 = ((2 * wn2 + 1) * 2 + nt) * 32 + nl;
    float v0 = pv[i0], v1 = pv[i1];
    int   j0 = pi[i0], j1 = pi[i1];
    if (v1 < v0 || (v1 == v0 && j1 < j0)) { v0 = v1; j0 = j1; }
    unsigned long long pk = ((unsigned long long)ford(v0) << 32) | (unsigned)j0;
    atomicMin(&mind64[(size_t)b * NN_ + n0 + t], pk);
  }
}

// ---------- kernel 5: 16-block histogram of mind64 -> (last block) scan -> cursor ; out_denom ----------
__global__ __launch_bounds__(256) void k_scan(const unsigned long long* __restrict__ mind64,
                                              const float* __restrict__ ema_denom,
                                              int* __restrict__ hist,
                                              int* __restrict__ done,
                                              int* __restrict__ cursor,
                                              float* __restrict__ out_denom) {
  __shared__ int h[KK];
  __shared__ int ps[256];
  __shared__ int lastFlag;
  const int t = threadIdx.x;
#pragma unroll
  for (int i = 0; i < 8; i++) h[t + 256 * i] = 0;
  __syncthreads();
  const int base = blockIdx.x * (NG / 16);
#pragma unroll
  for (int i = 0; i < NG / 16 / 256; i++) {   // 8 iters of 256
    int idx = (int)(mind64[base + i * 256 + t] & 0xFFFFFFFFULL);
    atomicAdd(&h[idx], 1);
  }
  __syncthreads();
#pragma unroll
  for (int i = 0; i < 8; i++) {
    int v = h[t + 256 * i];
    if (v) atomicAdd(&hist[t + 256 * i], v);
  }
  __threadfence();
  __syncthreads();
  if (t == 0) lastFlag = (atomicAdd(done, 1) == 15);
  __syncthreads();
  if (!lastFlag) return;

  // last block: read hist coherently (device-scope atomic read), scan, emit
  int c[8], s = 0;
#pragma unroll
  for (int e = 0; e < 8; e++) { c[e] = atomicAdd(&hist[8 * t + e], 0); s += c[e]; }
  ps[t] = s;
  __syncthreads();
  for (int off = 1; off < 256; off <<= 1) {
    int v = (t >= off) ? ps[t - off] : 0;
    __syncthreads();
    ps[t] += v;
    __syncthreads();
  }
  int run = ps[t] - s;
#pragma unroll
  for (int e = 0; e < 8; e++) {
    cursor[8 * t + e] = run;
    out_denom[8 * t + e] = 0.99f * ema_denom[8 * t + e]
                         + 0.009999999776482582f * (float)c[e];
    run += c[e];
  }
}

// ---------- kernel 6: out[b,d,n] = emb[mind[b,n], d] ; fused pos-scatter ----------
__global__ __launch_bounds__(256) void k_out(const float* __restrict__ emb,
                                             const unsigned long long* __restrict__ mind64,
                                             float* __restrict__ out,
                                             int* __restrict__ cursor,
                                             int* __restrict__ sortp) {
  __shared__ __align__(16) float E[64][257];
  __shared__ int idxl[64];
  const int t = threadIdx.x;
  const int b  = blockIdx.y;
  const int n0 = blockIdx.x * 64;
  if (t < 64) idxl[t] = (int)(mind64[(size_t)b * NN_ + n0 + t] & 0xFFFFFFFFULL);
  __syncthreads();

  // fused k_pos: scatter these 64 samples into sorted order
  if (t < 64) {
    int g = b * NN_ + n0 + t;
    int k = idxl[t];
    int p = atomicAdd(&cursor[k], 1);
    sortp[p] = (k << 15) | g;
  }

  for (int i = 0; i < 16; i++) {
    int cid = t + 256 * i;
    int r = cid >> 6, q = cid & 63;
    float4 v = *(const float4*)&emb[(size_t)idxl[r] * DD + 4 * q];
    float* vp = (float*)&v;
    E[r][4 * q + 0] = vp[0];
    E[r][4 * q + 1] = vp[1];
    E[r][4 * q + 2] = vp[2];
    E[r][4 * q + 3] = vp[3];
  }
  __syncthreads();
  const int nq = t & 15, dg = t >> 4;
  float* outb = out + (size_t)b * DD * NN_ + n0;
#pragma unroll
  for (int i = 0; i < 16; i++) {
    int d = i * 16 + dg;
    float4 v = make_float4(E[4 * nq + 0][d], E[4 * nq + 1][d],
                           E[4 * nq + 2][d], E[4 * nq + 3][d]);
    *(float4*)&outb[(size_t)d * NN_ + 4 * nq] = v;
  }
}

// ---------- kernel 7: segment-sum over sorted runs -> out_numer += OG*z_sum ----------
// widened: 256 blocks, 32 entries per wave
__global__ __launch_bounds__(256) void k_zsum(const int* __restrict__ sortp,
                                              const _Float16* __restrict__ zeT_h,
                                              const _Float16* __restrict__ zeT_l,
                                              float* __restrict__ out_numer) {
  const float OG = 0.009999999776482582f;
  __shared__ int sg[128];
  const int t = threadIdx.x;
  const int w = t >> 6, lane = t & 63;
  if (t < 128) sg[t] = sortp[blockIdx.x * 128 + t];
  __syncthreads();
  const int base = w * 32;
  float acc[4] = {0.f, 0.f, 0.f, 0.f};
  int cur = sg[base] >> 15;
  for (int j = 0; j < 32; j++) {
    int e = sg[base + j];
    int k = e >> 15, g = e & 32767;
    if (k != cur) {
      float* zs = &out_numer[(size_t)cur * DD + 4 * lane];
#pragma unroll
      for (int x = 0; x < 4; x++) { atomicAdd(&zs[x], OG * acc[x]); acc[x] = 0.f; }
      cur = k;
    }
    f16x4 h = *(const f16x4*)&zeT_h[(size_t)g * DD + 4 * lane];
    f16x4 l = *(const f16x4*)&zeT_l[(size_t)g * DD + 4 * lane];
#pragma unroll
    for (int x = 0; x < 4; x++) acc[x] += (float)h[x] + (float)l[x];
  }
  float* zs = &out_numer[(size_t)cur * DD + 4 * lane];
#pragma unroll
  for (int x = 0; x < 4; x++) atomicAdd(&zs[x], OG * acc[x]);
}

extern "C" void kernel_launch(void* const* d_in, const int* in_sizes, int n_in,
                              void* d_out, int out_size, void* d_ws, size_t ws_size,
                              hipStream_t stream) {
  (void)in_sizes; (void)n_in; (void)out_size; (void)ws_size;
  const float* z         = (const float*)d_in[0];
  const float* W         = (const float*)d_in[1];
  const float* emb       = (const float*)d_in[2];
  const float* ema_numer = (const float*)d_in[3];
  const float* ema_denom = (const float*)d_in[4];

  float* out       = (float*)d_out;                        // (8,256,4096)
  float* out_numer = out + (size_t)B_ * DD * NN_;
  float* out_denom = out_numer + (size_t)KK * DD;

  const size_t ZET = (size_t)B_ * NN_ * DD;                // 8388608
  _Float16* zeT_h = (_Float16*)d_ws;                       // 16 MB
  _Float16* zeT_l = zeT_h + ZET;                           // 16 MB
  float* esq    = (float*)(zeT_l + ZET);                   // 2048 f
  int*   cursor = (int*)(esq + KK);                        // 2048 i
  int*   sortp  = cursor + KK;                             // 32768 i
  unsigned long long* mind64 = (unsigned long long*)(sortp + NG);  // 32768 u64 (8B-aligned)
  int*   hist   = (int*)(mind64 + NG);                     // 2048 i
  int*   done   = hist + KK;                               // 256 i
  _Float16* emb_h = (_Float16*)(done + 256);               // 524288 f16
  _Float16* emb_l = emb_h + (size_t)KK * DD;               // 524288 f16

  // k_init0 grid: 512 esq-blocks + (KK*DD + 2*NG + KK + 256)/256 init-blocks
  const int initBlocks = KK / 4 + (KK * DD + 2 * NG + KK + 256) / 256;   // 512 + 2313
  k_init0<<<dim3(initBlocks), 256, 0, stream>>>(emb, ema_numer, esq, emb_h, emb_l,
                                                out_numer, (unsigned*)mind64, hist, done);
  k_ze<<<dim3(NN_ / 128, DD / 128, B_), 256, 0, stream>>>(W, z, zeT_h, zeT_l);
  k_argmin<<<dim3(NN_ / 128, B_, KSPLIT), 256, 0, stream>>>(emb_h, emb_l, zeT_h, zeT_l,
                                                            esq, mind64);
  k_scan<<<dim3(16), 256, 0, stream>>>(mind64, ema_denom, hist, done, cursor, out_denom);
  k_out<<<dim3(NN_ / 64, B_), 256, 0, stream>>>(emb, mind64, out, cursor, sortp);
  k_zsum<<<dim3(NG / 128), 256, 0, stream>>>(sortp, zeT_h, zeT_l, out_numer);
}